// Round 1
// baseline (314.187 us; speedup 1.0000x reference)
//
#include <hip/hip_runtime.h>

typedef float v2f __attribute__((ext_vector_type(2)));

#define TX 64
#define TY 20                 // output rows per chunk
#define WIN 30                // h-rows needed per chunk window (TY + 10)
#define RING 30               // LDS row ring (== WIN; 20c mod 30 cycles {0,20,10})
#define HSTR 65               // col stride: 5*65=325 ≡ 5 (mod 32) -> 2-way writes (free)
#define IMW 512
#define IMH 512
#define NPLANES 96            // 32 * 3
#define NBX (IMW / TX)        // 8
#define NCHUNK ((IMH + TY - 1) / TY)   // 26 (last chunk rows 500..519, masked)
#define NBLOCKS (NBX * NPLANES)        // 768 = exactly 3 blocks/CU, all resident

// Gaussian(sigma=1.5, ws=11), double-computed, fp32-rounded.
#define GW0 0.00102838f
#define GW1 0.00759877f
#define GW2 0.03600077f
#define GW3 0.10936069f
#define GW4 0.21300553f
#define GW5 0.26601172f

__device__ __forceinline__ void pkfma(v2f& acc, v2f a, v2f b) {
  asm("v_pk_fma_f32 %0, %1, %2, %0" : "+v"(acc) : "v"(a), "v"(b));
}
__device__ __forceinline__ v2f pkmul(v2f a, v2f b) {
  v2f d;
  asm("v_pk_mul_f32 %0, %1, %2" : "=v"(d) : "v"(a), "v"(b));
  return d;
}

// Horizontal 11-tap blur of `nrows` rows starting at image row gy0, written
// into ring slots slot0.. (mod RING). Thread t (t < nrows*8): row t>>3,
// 8-col run starting at (t&7)*8. Window = 24 cols loaded as 6 aligned float4.
__device__ __forceinline__ void hblur(
    const float* __restrict__ gp, const float* __restrict__ rp,
    float* __restrict__ sq, int x0, bool interior_x,
    int nrows, int gy0, int slot0, int tid) {
  if (tid >= nrows * 8) return;
  const float GW[11] = {GW0, GW1, GW2, GW3, GW4, GW5,
                        GW4, GW3, GW2, GW1, GW0};
  const int r = tid >> 3;
  const int xs = (tid & 7) * 8;
  const int gy = gy0 + r;
  int slot = slot0 + r;
  if (slot >= RING) slot -= RING;
  const int xbase = x0 + xs - 8;  // window cols [xbase, xbase+24)
  const float* grow = gp + (size_t)gy * IMW;
  const float* rrow = rp + (size_t)gy * IMW;

  v2f P[24];  // (g, r) transformed, packed per column
  const bool rowok = (gy >= 0) & (gy < IMH);
  if (interior_x & rowok) {
#pragma unroll
    for (int k = 0; k < 6; ++k) {
      const int c = xbase + 4 * k;
      const float4 g4 = *(const float4*)(grow + c);
      const float4 r4 = *(const float4*)(rrow + c);
      P[4 * k + 0] = (v2f){fmaf(0.5f, g4.x, 0.5f), fmaf(0.5f, r4.x, 0.5f)};
      P[4 * k + 1] = (v2f){fmaf(0.5f, g4.y, 0.5f), fmaf(0.5f, r4.y, 0.5f)};
      P[4 * k + 2] = (v2f){fmaf(0.5f, g4.z, 0.5f), fmaf(0.5f, r4.z, 0.5f)};
      P[4 * k + 3] = (v2f){fmaf(0.5f, g4.w, 0.5f), fmaf(0.5f, r4.w, 0.5f)};
    }
  } else {
#pragma unroll
    for (int k = 0; k < 6; ++k) {
      const int c = xbase + 4 * k;
      const bool ok = rowok && (c >= 0) && (c < IMW);
      float4 g4 = make_float4(-1.f, -1.f, -1.f, -1.f);
      float4 r4 = g4;  // transform maps -1 -> 0 (matches zero padding)
      if (ok) {
        g4 = *(const float4*)(grow + c);
        r4 = *(const float4*)(rrow + c);
      }
      P[4 * k + 0] = (v2f){fmaf(0.5f, g4.x, 0.5f), fmaf(0.5f, r4.x, 0.5f)};
      P[4 * k + 1] = (v2f){fmaf(0.5f, g4.y, 0.5f), fmaf(0.5f, r4.y, 0.5f)};
      P[4 * k + 2] = (v2f){fmaf(0.5f, g4.z, 0.5f), fmaf(0.5f, r4.z, 0.5f)};
      P[4 * k + 3] = (v2f){fmaf(0.5f, g4.w, 0.5f), fmaf(0.5f, r4.w, 0.5f)};
    }
  }

  v2f accP[8], accQ[8];
  float accS[8];
#pragma unroll
  for (int o = 0; o < 8; ++o) {
    accP[o] = (v2f){0.f, 0.f};
    accQ[o] = (v2f){0.f, 0.f};
    accS[o] = 0.f;
  }

#pragma unroll
  for (int p = 0; p < 18; ++p) {  // window position; col value = P[p+3]
    const v2f pv = P[p + 3];
    const v2f qv = pkmul(pv, pv);
    const float sv = pv.x * pv.y;
    const int olo = (p - 10 < 0) ? 0 : p - 10;
    const int ohi = (p < 7) ? p : 7;
#pragma unroll
    for (int o = olo; o <= ohi; ++o) {
      const float wt = GW[p - o];
      const v2f wv = (v2f){wt, wt};
      pkfma(accP[o], wv, pv);
      pkfma(accQ[o], wv, qv);
      accS[o] = fmaf(wt, sv, accS[o]);
    }
  }

  // Layout [slot][5][HSTR]: P.x/P.y (and Q.x/Q.y) are 65 dwords apart ->
  // phase-2 pairs them into ds_read2_b32. Scalar stores pair along cols.
  float* dst = sq + slot * (5 * HSTR) + xs;
#pragma unroll
  for (int o = 0; o < 8; ++o) dst[0 * HSTR + o] = accP[o].x;
#pragma unroll
  for (int o = 0; o < 8; ++o) dst[1 * HSTR + o] = accP[o].y;
#pragma unroll
  for (int o = 0; o < 8; ++o) dst[2 * HSTR + o] = accQ[o].x;
#pragma unroll
  for (int o = 0; o < 8; ++o) dst[3 * HSTR + o] = accQ[o].y;
#pragma unroll
  for (int o = 0; o < 8; ++o) dst[4 * HSTR + o] = accS[o];
}

__global__ __launch_bounds__(256, 4) void ssim_main(
    const float* __restrict__ gen, const float* __restrict__ ref,
    double* __restrict__ partial) {
  // Rolling ring of 30 h-blurred rows per 64-col strip. Each chunk computes
  // only 20 NEW rows (prologue: 30), killing the old 1.5x phase-1 redundancy.
  __shared__ float s_q[RING][5][HSTR];  // 39,000 B -> 4 blocks/CU capacity
  __shared__ double swsum[4];

  const float GW[11] = {GW0, GW1, GW2, GW3, GW4, GW5,
                        GW4, GW3, GW2, GW1, GW0};

  const int tid = threadIdx.x;
  const int bid = blockIdx.x;
  const int bx = bid & (NBX - 1);
  const int plane = bid >> 3;
  const int x0 = bx * TX;
  const float* gp = gen + (size_t)plane * (IMW * IMH);
  const float* rp = ref + (size_t)plane * (IMW * IMH);
  const bool interior_x = (bx >= 1) & (bx <= NBX - 2);

  const int col = tid & 63;
  // wave-uniform: force scalar so ring addressing stays on the SALU
  const int r0 = __builtin_amdgcn_readfirstlane((tid >> 6) * 5);

  double acc = 0.0;

  // Prologue: h-rows gy = -5..24 -> slots 0..29 (30 rows, 240 threads).
  hblur(gp, rp, &s_q[0][0][0], x0, interior_x, WIN, -5, 0, tid);

  int base = 0;  // (TY*c) mod RING, cycles 0,20,10
  for (int c = 0; c < NCHUNK; ++c) {
    if (c > 0) {
      // New h-rows gy in [20c+5, 20c+25) -> slots (base+10).. (20 rows).
      // These overwrite rows gy-30 in [20c-25, 20c-5): aged out of window.
      int s0 = base + 10;
      if (s0 >= RING) s0 -= RING;
      hblur(gp, rp, &s_q[0][0][0], x0, interior_x, TY, TY * c + 5, s0, tid);
    }
    __syncthreads();  // phase-1 writes -> phase-2 reads

    // ---- Phase 2: vertical 11-tap blur + SSIM. 64 cols x 4 waves x 5 rows.
    int b2 = base + r0;
    if (b2 >= RING) b2 -= RING;
    v2f hp[15], hq[15];
    float hs[15];
#pragma unroll
    for (int i = 0; i < 15; ++i) {
      int slot = b2 + i;
      if (slot >= RING) slot -= RING;
      const float* rowp = &s_q[slot][0][col];
      hp[i] = (v2f){rowp[0 * HSTR], rowp[1 * HSTR]};  // ds_read2_b32
      hq[i] = (v2f){rowp[2 * HSTR], rowp[3 * HSTR]};  // ds_read2_b32
      hs[i] = rowp[4 * HSTR];
    }

    const float C1 = 6.5025f, C2 = 58.5225f;
    float lsum = 0.f;
#pragma unroll
    for (int o = 0; o < 5; ++o) {
      v2f mu = (v2f){0.f, 0.f};
      v2f ee = (v2f){0.f, 0.f};
      float e12 = 0.f;
#pragma unroll
      for (int t = 0; t < 11; ++t) {
        const float wt = GW[t];
        const v2f wv = (v2f){wt, wt};
        pkfma(mu, wv, hp[o + t]);
        pkfma(ee, wv, hq[o + t]);
        e12 = fmaf(wt, hs[o + t], e12);
      }
      const float mu1 = mu.x, mu2 = mu.y, e1 = ee.x, e2 = ee.y;
      const float m12 = mu1 * mu2;
      const float m1s = mu1 * mu1;
      const float m2s = mu2 * mu2;
      const float num = (2.f * m12 + C1) * (2.f * (e12 - m12) + C2);
      const float den = (m1s + m2s + C1) * ((e1 - m1s) + (e2 - m2s) + C2);
      const int y = TY * c + r0 + o;
      lsum += (y < IMH) ? __fdividef(num, den) : 0.f;
    }
    acc += (double)lsum;

    __syncthreads();  // phase-2 reads done -> next phase-1 may overwrite
    base += TY;
    if (base >= RING) base -= RING;
  }

  // Block reduction -> one deterministic double partial per strip.
#pragma unroll
  for (int off = 32; off > 0; off >>= 1) acc += __shfl_down(acc, off, 64);
  if ((tid & 63) == 0) swsum[tid >> 6] = acc;
  __syncthreads();
  if (tid == 0) partial[bid] = swsum[0] + swsum[1] + swsum[2] + swsum[3];
}

__global__ void ssim_reduce(const double* __restrict__ partial,
                            float* __restrict__ out) {
  const int tid = threadIdx.x;
  // 768 = 3 * 256 partials, fixed-order double sum (deterministic).
  double s = partial[tid] + partial[tid + 256] + partial[tid + 512];
#pragma unroll
  for (int off = 32; off > 0; off >>= 1) s += __shfl_down(s, off, 64);
  __shared__ double sd[4];
  if ((tid & 63) == 0) sd[tid >> 6] = s;
  __syncthreads();
  if (tid == 0) {
    const double npix = (double)NPLANES * (double)IMW * (double)IMH;
    out[0] = (float)(1.0 - (sd[0] + sd[1] + sd[2] + sd[3]) / npix);
  }
}

extern "C" void kernel_launch(void* const* d_in, const int* in_sizes, int n_in,
                              void* d_out, int out_size, void* d_ws, size_t ws_size,
                              hipStream_t stream) {
  (void)in_sizes; (void)n_in; (void)out_size; (void)ws_size;
  const float* gen = (const float*)d_in[0];
  const float* ref = (const float*)d_in[1];
  double* partial = (double*)d_ws;  // NBLOCKS doubles; every slot written each call
  ssim_main<<<NBLOCKS, 256, 0, stream>>>(gen, ref, partial);
  ssim_reduce<<<1, 256, 0, stream>>>(partial, (float*)d_out);
}

// Round 2
// 278.878 us; speedup vs baseline: 1.1266x; 1.1266x over previous
//
#include <hip/hip_runtime.h>

typedef float v2f __attribute__((ext_vector_type(2)));

#define TX 64
#define TY 20                // output rows per chunk
#define MY 2                 // chunks per block
#define BYR (TY * MY)        // 40 output rows per block
#define WIN 30               // LDS ring rows (TY + 10)
#define HSTR 65              // col stride: row stride 5*65=325 ≡ 5 (mod 32)
#define IMW 512
#define IMH 512
#define NPLANES 96           // 32 * 3
#define NBX (IMW / TX)       // 8
#define NBY ((IMH + BYR - 1) / BYR)    // 13 (last block rows 480..519, masked)
#define NBLOCKS (NBX * NBY * NPLANES)  // 9984

// Gaussian(sigma=1.5, ws=11), double-computed, fp32-rounded.
#define GW0 0.00102838f
#define GW1 0.00759877f
#define GW2 0.03600077f
#define GW3 0.10936069f
#define GW4 0.21300553f
#define GW5 0.26601172f

__device__ __forceinline__ void pkfma(v2f& acc, v2f a, v2f b) {
  asm("v_pk_fma_f32 %0, %1, %2, %0" : "+v"(acc) : "v"(a), "v"(b));
}
__device__ __forceinline__ v2f pkmul(v2f a, v2f b) {
  v2f d;
  asm("v_pk_mul_f32 %0, %1, %2" : "=v"(d) : "v"(a), "v"(b));
  return d;
}

// Raw global window for one h-blur row-run: 24 cols of gen + ref.
struct Raw {
  float4 g[6];
  float4 r[6];
};

// Issue global loads for `nrows` rows starting at image row gy0.
// Thread t (t < nrows*8): row t>>3, 8-col output run starting (t&7)*8.
__device__ __forceinline__ void hload(
    const float* __restrict__ gp, const float* __restrict__ rp,
    int x0, bool fast, int nrows, int gy0, int tid, Raw& L) {
  if (tid >= nrows * 8) return;
  const int r = tid >> 3;
  const int xs = (tid & 7) * 8;
  const int gy = gy0 + r;
  const int xbase = x0 + xs - 8;  // window cols [xbase, xbase+24)
  const float* grow = gp + (size_t)gy * IMW;
  const float* rrow = rp + (size_t)gy * IMW;
  if (fast) {
#pragma unroll
    for (int k = 0; k < 6; ++k) {
      L.g[k] = *(const float4*)(grow + xbase + 4 * k);
      L.r[k] = *(const float4*)(rrow + xbase + 4 * k);
    }
  } else {
    const bool rowok = (gy >= 0) & (gy < IMH);
#pragma unroll
    for (int k = 0; k < 6; ++k) {
      const int c = xbase + 4 * k;
      const bool ok = rowok && (c >= 0) && (c < IMW);
      float4 g4 = make_float4(-1.f, -1.f, -1.f, -1.f);
      float4 r4 = g4;  // transform maps -1 -> 0 (matches zero padding)
      if (ok) {
        g4 = *(const float4*)(grow + c);
        r4 = *(const float4*)(rrow + c);
      }
      L.g[k] = g4;
      L.r[k] = r4;
    }
  }
}

// Horizontal 11-tap blur from prefetched registers -> LDS ring slots
// slot0+r (r = tid>>3). Layout [slot][5][HSTR].
__device__ __forceinline__ void hcompute(
    const Raw& L, float* __restrict__ sq, int nrows, int slot0, int tid) {
  if (tid >= nrows * 8) return;
  const float GW[11] = {GW0, GW1, GW2, GW3, GW4, GW5,
                        GW4, GW3, GW2, GW1, GW0};
  const int r = tid >> 3;
  const int xs = (tid & 7) * 8;
  int slot = slot0 + r;
  if (slot >= WIN) slot -= WIN;

  v2f P[24];  // (g, r) transformed, packed per column
#pragma unroll
  for (int k = 0; k < 6; ++k) {
    const float4 g4 = L.g[k];
    const float4 r4 = L.r[k];
    P[4 * k + 0] = (v2f){fmaf(0.5f, g4.x, 0.5f), fmaf(0.5f, r4.x, 0.5f)};
    P[4 * k + 1] = (v2f){fmaf(0.5f, g4.y, 0.5f), fmaf(0.5f, r4.y, 0.5f)};
    P[4 * k + 2] = (v2f){fmaf(0.5f, g4.z, 0.5f), fmaf(0.5f, r4.z, 0.5f)};
    P[4 * k + 3] = (v2f){fmaf(0.5f, g4.w, 0.5f), fmaf(0.5f, r4.w, 0.5f)};
  }

  v2f accP[8], accQ[8];
  float accS[8];
#pragma unroll
  for (int o = 0; o < 8; ++o) {
    accP[o] = (v2f){0.f, 0.f};
    accQ[o] = (v2f){0.f, 0.f};
    accS[o] = 0.f;
  }

#pragma unroll
  for (int p = 0; p < 18; ++p) {  // window position; col value = P[p+3]
    const v2f pv = P[p + 3];
    const v2f qv = pkmul(pv, pv);
    const float sv = pv.x * pv.y;
    const int olo = (p - 10 < 0) ? 0 : p - 10;
    const int ohi = (p < 7) ? p : 7;
#pragma unroll
    for (int o = olo; o <= ohi; ++o) {
      const float wt = GW[p - o];
      const v2f wv = (v2f){wt, wt};
      pkfma(accP[o], wv, pv);
      pkfma(accQ[o], wv, qv);
      accS[o] = fmaf(wt, sv, accS[o]);
    }
  }

  // P.x/P.y (Q.x/Q.y) are 65 dwords apart -> phase-2 ds_read2_b32 pairs.
  float* dst = sq + slot * (5 * HSTR) + xs;
#pragma unroll
  for (int o = 0; o < 8; ++o) dst[0 * HSTR + o] = accP[o].x;
#pragma unroll
  for (int o = 0; o < 8; ++o) dst[1 * HSTR + o] = accP[o].y;
#pragma unroll
  for (int o = 0; o < 8; ++o) dst[2 * HSTR + o] = accQ[o].x;
#pragma unroll
  for (int o = 0; o < 8; ++o) dst[3 * HSTR + o] = accQ[o].y;
#pragma unroll
  for (int o = 0; o < 8; ++o) dst[4 * HSTR + o] = accS[o];
}

// Vertical 11-tap blur + SSIM for 5 output rows. winbase/r0 wave-uniform.
__device__ __forceinline__ float phase2(
    const float* __restrict__ sq, int winbase, int ybase, int col, int r0) {
  const float GW[11] = {GW0, GW1, GW2, GW3, GW4, GW5,
                        GW4, GW3, GW2, GW1, GW0};
  v2f hp[15], hq[15];
  float hs[15];
#pragma unroll
  for (int i = 0; i < 15; ++i) {
    int slot = winbase + r0 + i;
    if (slot >= WIN) slot -= WIN;
    const float* rowp = sq + slot * (5 * HSTR) + col;
    hp[i] = (v2f){rowp[0 * HSTR], rowp[1 * HSTR]};  // ds_read2_b32
    hq[i] = (v2f){rowp[2 * HSTR], rowp[3 * HSTR]};  // ds_read2_b32
    hs[i] = rowp[4 * HSTR];
  }

  const float C1 = 6.5025f, C2 = 58.5225f;
  float lsum = 0.f;
#pragma unroll
  for (int o = 0; o < 5; ++o) {
    v2f mu = (v2f){0.f, 0.f};
    v2f ee = (v2f){0.f, 0.f};
    float e12 = 0.f;
#pragma unroll
    for (int t = 0; t < 11; ++t) {
      const float wt = GW[t];
      const v2f wv = (v2f){wt, wt};
      pkfma(mu, wv, hp[o + t]);
      pkfma(ee, wv, hq[o + t]);
      e12 = fmaf(wt, hs[o + t], e12);
    }
    const float mu1 = mu.x, mu2 = mu.y, e1 = ee.x, e2 = ee.y;
    const float m12 = mu1 * mu2;
    const float m1s = mu1 * mu1;
    const float m2s = mu2 * mu2;
    const float num = (2.f * m12 + C1) * (2.f * (e12 - m12) + C2);
    const float den = (m1s + m2s + C1) * ((e1 - m1s) + (e2 - m2s) + C2);
    const int y = ybase + r0 + o;
    lsum += (y < IMH) ? __fdividef(num, den) : 0.f;
  }
  return lsum;
}

__global__ __launch_bounds__(256, 4) void ssim_main(
    const float* __restrict__ gen, const float* __restrict__ ref,
    double* __restrict__ partial) {
  // 2-chunk block: 40 output rows from a 30-row LDS ring.
  // Phase-1 rows per block: 30 + 20 = 50 (vs 2x30=60 for two 1-chunk blocks).
  // Chunk-1 global loads are register-prefetched under phase2(chunk0).
  __shared__ float s_q[WIN][5][HSTR];  // 39,000 B -> 4 blocks/CU
  __shared__ double swsum[4];
  float* const sq = &s_q[0][0][0];

  const int tid = threadIdx.x;
  const int bid = blockIdx.x;
  const int bx = bid & (NBX - 1);
  const int rem = bid >> 3;
  const int by = rem % NBY;
  const int plane = rem / NBY;
  const int x0 = bx * TX;
  const int Y0 = by * BYR;
  const float* gp = gen + (size_t)plane * (IMW * IMH);
  const float* rp = ref + (size_t)plane * (IMW * IMH);
  const bool ix = (bx >= 1) & (bx <= NBX - 2);

  const int col = tid & 63;
  // wave-uniform: keep ring addressing on the SALU
  const int r0 = __builtin_amdgcn_readfirstlane((tid >> 6) * 5);

  // Chunk 0: h-rows [Y0-5, Y0+25) -> slots 0..29.
  Raw L0;
  hload(gp, rp, x0, ix & (Y0 - 5 >= 0) & (Y0 + 25 <= IMH), WIN, Y0 - 5, tid, L0);
  hcompute(L0, sq, WIN, 0, tid);

  // Prefetch chunk 1: h-rows [Y0+25, Y0+45) -> will land in slots 0..19.
  Raw L1;
  hload(gp, rp, x0, ix & (Y0 + 45 <= IMH), TY, Y0 + 25, tid, L1);

  __syncthreads();  // phase-1 writes -> phase-2 reads (L1 loads in flight)

  double acc = (double)phase2(sq, 0, Y0, col, r0);

  __syncthreads();  // phase-2(0) reads done -> slots 0..19 may be overwritten

  hcompute(L1, sq, TY, 0, tid);

  __syncthreads();  // phase-1 writes -> phase-2 reads

  // Window rows [Y0+15, Y0+45) live in slots 20..29, 0..19 -> winbase 20.
  acc += (double)phase2(sq, 20, Y0 + TY, col, r0);

  // Block reduction -> one deterministic double partial per block.
#pragma unroll
  for (int off = 32; off > 0; off >>= 1) acc += __shfl_down(acc, off, 64);
  if ((tid & 63) == 0) swsum[tid >> 6] = acc;
  __syncthreads();
  if (tid == 0) partial[bid] = swsum[0] + swsum[1] + swsum[2] + swsum[3];
}

__global__ void ssim_reduce(const double* __restrict__ partial,
                            float* __restrict__ out) {
  const int tid = threadIdx.x;
  double s = 0.0;
  // 9984 = 39 * 256 partials, fixed-order per thread (deterministic).
  for (int i = tid; i < NBLOCKS; i += 256) s += partial[i];
#pragma unroll
  for (int off = 32; off > 0; off >>= 1) s += __shfl_down(s, off, 64);
  __shared__ double sd[4];
  if ((tid & 63) == 0) sd[tid >> 6] = s;
  __syncthreads();
  if (tid == 0) {
    const double npix = (double)NPLANES * (double)IMW * (double)IMH;
    out[0] = (float)(1.0 - (sd[0] + sd[1] + sd[2] + sd[3]) / npix);
  }
}

extern "C" void kernel_launch(void* const* d_in, const int* in_sizes, int n_in,
                              void* d_out, int out_size, void* d_ws, size_t ws_size,
                              hipStream_t stream) {
  (void)in_sizes; (void)n_in; (void)out_size; (void)ws_size;
  const float* gen = (const float*)d_in[0];
  const float* ref = (const float*)d_in[1];
  double* partial = (double*)d_ws;  // NBLOCKS doubles; every slot written each call
  ssim_main<<<NBLOCKS, 256, 0, stream>>>(gen, ref, partial);
  ssim_reduce<<<1, 256, 0, stream>>>(partial, (float*)d_out);
}